// Round 14
// baseline (154.974 us; speedup 1.0000x reference)
//
#include <hip/hip_runtime.h>
#include <hip/hip_bf16.h>

#define D 64
#define NG 64
#define CAP 64   // per-node CSR slot capacity (Poisson(16) degrees; P(>64)~1e-17)

typedef short bf16x8 __attribute__((ext_vector_type(8)));
typedef float f32x4  __attribute__((ext_vector_type(4)));

__device__ __forceinline__ float b2f(unsigned short u){
  return __uint_as_float(((unsigned)u) << 16);
}
__device__ __forceinline__ unsigned short f2bu(float f){
  return __builtin_bit_cast(unsigned short, __float2bfloat16(f));
}

// VALU-pipe 16-lane circular reduce step: x += row_ror<C>(x)
template<int C>
__device__ __forceinline__ float dppadd(float x){
  int t = __builtin_amdgcn_update_dpp(0, __float_as_int(x), C, 0xf, 0xf, true);
  return x + __int_as_float(t);
}

// ---------- pass 0: W-fragment precompute (8 blocks: one per matrix x k-half)
__global__ __launch_bounds__(256) void k_wprep(
    const float* __restrict__ Wq, const float* __restrict__ Wk,
    const float* __restrict__ Wv, const float* __restrict__ Ws,
    short* __restrict__ fragw)
{
  const int m    = blockIdx.x >> 1;
  const int kh   = blockIdx.x & 1;
  const int ct   = threadIdx.x >> 6;
  const int lane = threadIdx.x & 63;
  const int r16  = lane & 15;
  const int kg   = lane >> 4;
  const float* Wm = (m==0) ? Wq : (m==1) ? Wk : (m==2) ? Wv : Ws;
  short* base = fragw + (size_t)(m*64 + lane)*128;
  bf16x8 hi, lo;
  #pragma unroll
  for (int j = 0; j < 8; ++j){
    float wv = Wm[(32*kh + 8*kg + j)*D + 16*ct + r16];
    unsigned short hb = f2bu(wv);
    hi[j] = (short)hb;
    lo[j] = (short)f2bu(wv - b2f(hb));
  }
  int fi = ct*2 + kh;
  *(bf16x8*)(base + fi*8)      = hi;
  *(bf16x8*)(base + 64 + fi*8) = lo;
}

// ---------- pass 1 (fused): CSR slot-fill  ||  x@{Wq,Wk,Wv,Ws} via MFMA ------
// The two jobs are data-independent; serializing them wastes the 53 µs the
// scattered atomics spend saturating the memory-side atomic path (a measured
// HW floor: ILP1/ILP4/line-padding all ~50-57 µs). Fill blocks come FIRST in
// the grid so they seize CUs immediately; the 3125 short linear4 strip blocks
// churn through the remaining wave slots concurrently.
__global__ __launch_bounds__(256) void k_main(
    // fill part
    const int* __restrict__ esrc, const int* __restrict__ edst,
    int* __restrict__ cntp, unsigned short* __restrict__ slots, int E, int nFill,
    // linear4 part
    const float* __restrict__ x, const short* __restrict__ fragw,
    const float* __restrict__ bq, const float* __restrict__ bk,
    const float* __restrict__ bv, const float* __restrict__ bs,
    float* __restrict__ q, __hip_bfloat16* __restrict__ kb,
    __hip_bfloat16* __restrict__ vb, float* __restrict__ sp, int N)
{
  if ((int)blockIdx.x < nFill){
    // ---- CSR capacity-slot fill: 4 consecutive edges per thread ----
    int t = blockIdx.x*256 + threadIdx.x;
    int e0 = t*4;
    if (e0 + 3 < E){
      int4 s4 = *(const int4*)(esrc + e0);
      int4 d4 = *(const int4*)(edst + e0);
      int p0 = atomicAdd(cntp + (d4.x<<4), 1);
      int p1 = atomicAdd(cntp + (d4.y<<4), 1);
      int p2 = atomicAdd(cntp + (d4.z<<4), 1);
      int p3 = atomicAdd(cntp + (d4.w<<4), 1);
      if (p0 < CAP) slots[d4.x*CAP + p0] = (unsigned short)s4.x;
      if (p1 < CAP) slots[d4.y*CAP + p1] = (unsigned short)s4.y;
      if (p2 < CAP) slots[d4.z*CAP + p2] = (unsigned short)s4.z;
      if (p3 < CAP) slots[d4.w*CAP + p3] = (unsigned short)s4.w;
    } else if (e0 < E){
      for (int e = e0; e < E; ++e){
        int pos = atomicAdd(cntp + (edst[e]<<4), 1);
        if (pos < CAP) slots[edst[e]*CAP + pos] = (unsigned short)esrc[e];
      }
    }
    return;
  }

  // ---- linear4: one 16-row strip per block, straight-line MFMA body ----
  const int lane = threadIdx.x & 63;
  const int w    = threadIdx.x >> 6;   // wave id = matrix id
  const int r16  = lane & 15;
  const int kg   = lane >> 4;

  const float* bm = (w==0) ? bq : (w==1) ? bk : (w==2) ? bv : bs;

  const short* base = fragw + (size_t)(w*64 + lane)*128;
  bf16x8 wh[4][2], wl[4][2];
  #pragma unroll
  for (int fi = 0; fi < 8; ++fi){
    wh[fi>>1][fi&1] = *(const bf16x8*)(base + fi*8);
    wl[fi>>1][fi&1] = *(const bf16x8*)(base + 64 + fi*8);
  }

  const int R0 = (blockIdx.x - nFill) << 4;
  const float* xp = x + (size_t)(R0 + r16)*D + 8*kg;
  float4 a0 = *(const float4*)(xp);        // k-half0: k=8kg+0..3
  float4 a1 = *(const float4*)(xp + 4);    //          k=8kg+4..7
  float4 a2 = *(const float4*)(xp + 32);   // k-half1
  float4 a3 = *(const float4*)(xp + 36);

  bf16x8 xh[2], xl[2];
  {
    float t;
    unsigned short hb;
    #define PK(kh, j, val) t=(val); hb=f2bu(t); xh[kh][j]=(short)hb; \
                           xl[kh][j]=(short)f2bu(t - b2f(hb));
    PK(0,0,a0.x) PK(0,1,a0.y) PK(0,2,a0.z) PK(0,3,a0.w)
    PK(0,4,a1.x) PK(0,5,a1.y) PK(0,6,a1.z) PK(0,7,a1.w)
    PK(1,0,a2.x) PK(1,1,a2.y) PK(1,2,a2.z) PK(1,3,a2.w)
    PK(1,4,a3.x) PK(1,5,a3.y) PK(1,6,a3.z) PK(1,7,a3.w)
    #undef PK
  }

  #pragma unroll
  for (int ct = 0; ct < 4; ++ct){
    float bv_ = bm[16*ct + r16];
    f32x4 acc = {bv_, bv_, bv_, bv_};
    #pragma unroll
    for (int kh = 0; kh < 2; ++kh){
      acc = __builtin_amdgcn_mfma_f32_16x16x32_bf16(xh[kh], wh[ct][kh], acc, 0,0,0);
      acc = __builtin_amdgcn_mfma_f32_16x16x32_bf16(xh[kh], wl[ct][kh], acc, 0,0,0);
      acc = __builtin_amdgcn_mfma_f32_16x16x32_bf16(xl[kh], wh[ct][kh], acc, 0,0,0);
    }
    #pragma unroll
    for (int i = 0; i < 4; ++i){
      size_t o = (size_t)(R0 + 4*kg + i)*D + 16*ct + r16;
      if (w == 0)      q[o] = acc[i];
      else if (w == 1) ((unsigned short*)kb)[o] = f2bu(acc[i]);
      else if (w == 2) ((unsigned short*)vb)[o] = f2bu(acc[i]);
      else             sp[o] = acc[i];
    }
  }
}

// ---------- fused attention gather: logits + softmax + PV + skip + ReLU ----------
__global__ __launch_bounds__(256) void k_attend(
    const float* __restrict__ q, const __hip_bfloat16* __restrict__ kb,
    const __hip_bfloat16* __restrict__ vb, float* __restrict__ sp,
    const int* __restrict__ cntp, const unsigned short* __restrict__ slots, int N)
{
  int node = blockIdx.x*4 + (threadIdx.x >> 6);
  if (node >= N) return;
  const int lane = threadIdx.x & 63;
  const int grp  = lane >> 4;
  const int gl   = lane & 15;

  float4 q4 = ((const float4*)(q + (size_t)node*D))[gl];
  int dg = min(cntp[node<<4], CAP);
  int p0 = node*CAP;

  float den = 0.f;
  float ax=0.f, ay=0.f, az=0.f, aw=0.f;

  const unsigned short* ku = (const unsigned short*)kb;
  const unsigned short* vu = (const unsigned short*)vb;

  int sidx = (lane < dg) ? (int)slots[p0 + lane] : 0;   // dg <= CAP = 64
  int T = (dg + 3) >> 2;               // uniform trip count for all groups
  #pragma unroll 2
  for (int t = 0; t < T; ++t){
    int ei  = grp + 4*t;
    int eis = min(ei, dg - 1);         // clamped: always a valid source lane
    int s = __shfl(sidx, eis, 64);     // executed by all 64 lanes
    if (ei < dg){                      // group-uniform predicate
      ushort4 k4 = ((const ushort4*)(ku + (size_t)s*D))[gl];
      float p = q4.x*b2f(k4.x) + q4.y*b2f(k4.y)
              + q4.z*b2f(k4.z) + q4.w*b2f(k4.w);
      p = dppadd<0x121>(p);            // += row_ror:1
      p = dppadd<0x122>(p);            // += row_ror:2
      p = dppadd<0x124>(p);            // += row_ror:4
      p = dppadd<0x128>(p);            // += row_ror:8  -> 16-lane total
      float ex = __expf(fminf(p * 0.125f, 60.f));   // 1/sqrt(64)
      ushort4 v4 = ((const ushort4*)(vu + (size_t)s*D))[gl];
      den += ex;
      ax = fmaf(ex, b2f(v4.x), ax);
      ay = fmaf(ex, b2f(v4.y), ay);
      az = fmaf(ex, b2f(v4.z), az);
      aw = fmaf(ex, b2f(v4.w), aw);
    }
  }

  // merge the 4 groups (lanes gl, gl+16, gl+32, gl+48): plain sums
  #pragma unroll
  for (int off = 16; off <= 32; off <<= 1){
    den += __shfl_xor(den, off, 64);
    ax  += __shfl_xor(ax,  off, 64);
    ay  += __shfl_xor(ay,  off, 64);
    az  += __shfl_xor(az,  off, 64);
    aw  += __shfl_xor(aw,  off, 64);
  }

  if (grp == 0){
    float4 s4 = ((const float4*)(sp + (size_t)node*D))[gl];
    float4 o;
    if (dg > 0){
      float inv = 1.f/den;
      o.x = fmaf(ax, inv, s4.x);
      o.y = fmaf(ay, inv, s4.y);
      o.z = fmaf(az, inv, s4.z);
      o.w = fmaf(aw, inv, s4.w);
    } else {
      o = s4;
    }
    o.x = fmaxf(o.x, 0.f); o.y = fmaxf(o.y, 0.f);
    o.z = fmaxf(o.z, 0.f); o.w = fmaxf(o.w, 0.f);
    ((float4*)(sp + (size_t)node*D))[gl] = o;
  }
}

// ---------- mean pool: register accumulation per wave strip ----------
__global__ __launch_bounds__(256) void k_pool(
    const float* __restrict__ rows, const int* __restrict__ batch,
    float* __restrict__ gsum, float* __restrict__ gcnt, int N, int rpw)
{
  const int lane = threadIdx.x & 63;
  const int wid  = threadIdx.x >> 6;
  int wi = blockIdx.x*4 + wid;
  int start = wi * rpw;
  if (start >= N) return;
  int end = min(start + rpw, N);

  float acc = 0.f, cnt = 0.f;
  int gcur = batch[start];
  #pragma unroll 4
  for (int row = start; row < end; ++row){
    int g = batch[row];                     // wave-uniform scalar load
    float val = rows[(size_t)row*D + lane]; // coalesced 256B per wave
    if (g != gcur){
      atomicAdd(gsum + (size_t)gcur*D + lane, acc);
      if (lane == 0) atomicAdd(gcnt + gcur, cnt);
      acc = 0.f; cnt = 0.f; gcur = g;
    }
    acc += val;
    cnt += 1.f;
  }
  atomicAdd(gsum + (size_t)gcur*D + lane, acc);
  if (lane == 0) atomicAdd(gcnt + gcur, cnt);
}

__global__ __launch_bounds__(256) void k_final(
    const float* __restrict__ gsum, const float* __restrict__ gcnt,
    float* __restrict__ out, int n)
{
  int i = blockIdx.x*256 + threadIdx.x;
  if (i >= n) return;
  int g = i >> 6;
  out[i] = gsum[i] / fmaxf(gcnt[g], 1.0f);
}

extern "C" void kernel_launch(void* const* d_in, const int* in_sizes, int n_in,
                              void* d_out, int out_size, void* d_ws, size_t ws_size,
                              hipStream_t stream)
{
  const float* x   = (const float*)d_in[0];
  const int*  ei   = (const int*)d_in[1];
  const int*  batch= (const int*)d_in[2];
  const float* Wq  = (const float*)d_in[3];
  const float* bq  = (const float*)d_in[4];
  const float* Wk  = (const float*)d_in[5];
  const float* bk  = (const float*)d_in[6];
  const float* Wv  = (const float*)d_in[7];
  const float* bv  = (const float*)d_in[8];
  const float* Ws  = (const float*)d_in[9];
  const float* bs  = (const float*)d_in[10];
  float* out = (float*)d_out;

  const int N = in_sizes[0] / D;   // 50000
  const int E = in_sizes[1] / 2;   // 800000
  const int* esrc = ei;
  const int* edst = ei + E;

  float* ws = (float*)d_ws;
  size_t off = 0;
  float* q    = ws + off; off += (size_t)N*D;
  __hip_bfloat16* kb = (__hip_bfloat16*)(ws + off); off += (size_t)N*D/2;
  __hip_bfloat16* vb = (__hip_bfloat16*)(ws + off); off += (size_t)N*D/2;
  float* sp   = ws + off; off += (size_t)N*D;   // s-proj in, relu(out) in-place
  // zero region: [cntp (padded: 1 int per 64B line) | gsum | gcnt]
  int*   cntp = (int*)(ws + off);  off += (size_t)N*16;
  float* gsum = ws + off; off += (size_t)NG*D;
  float* gcnt = ws + off; off += NG;
  unsigned short* slots = (unsigned short*)(ws + off); off += (size_t)N*CAP/2;
  short* fragw = (short*)(ws + off); off += 4*64*128/2;   // 64 KB

  size_t zbytes = ((size_t)N*16 + (size_t)NG*D + NG) * sizeof(float);
  hipMemsetAsync((void*)cntp, 0, zbytes, stream);

  const int nFill = (E/4 + 255)/256;   // 782 fill blocks (first in grid)
  const int nLin  = N/16;              // 3125 linear4 strip blocks

  k_wprep<<<8, 256, 0, stream>>>(Wq, Wk, Wv, Ws, fragw);
  k_main <<<nFill + nLin, 256, 0, stream>>>(esrc, edst, cntp, slots, E, nFill,
                                            x, fragw, bq, bk, bv, bs,
                                            q, kb, vb, sp, N);
  k_attend<<<(N+3)/4, 256, 0, stream>>>(q, kb, vb, sp, cntp, slots, N);
  const int rpw = 32;
  int nwaves = (N + rpw - 1) / rpw;
  k_pool<<<(nwaves+3)/4, 256, 0, stream>>>(sp, batch, gsum, gcnt, N, rpw);
  k_final<<<(NG*D+255)/256, 256, 0, stream>>>(gsum, gcnt, out, NG*D);
}

// Round 15
// 118.007 us; speedup vs baseline: 1.3133x; 1.3133x over previous
//
#include <hip/hip_runtime.h>
#include <hip/hip_bf16.h>

#define D 64
#define NG 64
#define CAP 64      // per-node slot capacity (Poisson(16); P(>64)~1e-17)
#define NB 196      // dst buckets: bucket = dst>>8 (49999>>8 = 195)
#define BCAP 5120   // per-bucket edge capacity (mean 4096, +16 sigma)

typedef short bf16x8 __attribute__((ext_vector_type(8)));
typedef float f32x4  __attribute__((ext_vector_type(4)));

__device__ __forceinline__ float b2f(unsigned short u){
  return __uint_as_float(((unsigned)u) << 16);
}
__device__ __forceinline__ unsigned short f2bu(float f){
  return __builtin_bit_cast(unsigned short, __float2bfloat16(f));
}

// VALU-pipe 16-lane circular reduce step: x += row_ror<C>(x)
template<int C>
__device__ __forceinline__ float dppadd(float x){
  int t = __builtin_amdgcn_update_dpp(0, __float_as_int(x), C, 0xf, 0xf, true);
  return x + __int_as_float(t);
}

// ---------- pass 0: W-fragment precompute ----------
// Layout [fi][part][m][lane] so a linear4 frag-load instruction reads 64
// lanes x contiguous 16B (16 cache lines), not 64 lines at 256B lane stride.
__global__ __launch_bounds__(256) void k_wprep(
    const float* __restrict__ Wq, const float* __restrict__ Wk,
    const float* __restrict__ Wv, const float* __restrict__ Ws,
    short* __restrict__ fragw)
{
  const int m    = blockIdx.x >> 1;
  const int kh   = blockIdx.x & 1;
  const int ct   = threadIdx.x >> 6;
  const int lane = threadIdx.x & 63;
  const int r16  = lane & 15;
  const int kg   = lane >> 4;
  const float* Wm = (m==0) ? Wq : (m==1) ? Wk : (m==2) ? Wv : Ws;
  bf16x8 hi, lo;
  #pragma unroll
  for (int j = 0; j < 8; ++j){
    float wv = Wm[(32*kh + 8*kg + j)*D + 16*ct + r16];
    unsigned short hb = f2bu(wv);
    hi[j] = (short)hb;
    lo[j] = (short)f2bu(wv - b2f(hb));
  }
  int fi = ct*2 + kh;
  *(bf16x8*)(fragw + ((size_t)(fi*2+0)*256 + m*64 + lane)*8) = hi;
  *(bf16x8*)(fragw + ((size_t)(fi*2+1)*256 + m*64 + lane)*8) = lo;
}

// ---------- CSR build phase 1: LDS multisplit into dst-range buckets --------
// Per-wg LDS histogram over NB buckets -> ONE global reserve atomic per
// (wg, bucket) = 50K total (vs 800K scattered) -> scatter packed edges.
__global__ __launch_bounds__(256) void k_split(
    const int* __restrict__ esrc, const int* __restrict__ edst,
    int* __restrict__ bcnt, unsigned* __restrict__ bedge, int E, int nChunk)
{
  __shared__ int hist[NB], gpos[NB], cur[NB];
  const int tid = threadIdx.x;
  if (tid < NB){ hist[tid] = 0; cur[tid] = 0; }
  __syncthreads();
  const int c0 = blockIdx.x * nChunk;
  const int c1 = min(c0 + nChunk, E);
  for (int e = c0 + tid; e < c1; e += 256)
    atomicAdd(&hist[edst[e] >> 8], 1);
  __syncthreads();
  if (tid < NB && hist[tid] > 0)
    gpos[tid] = atomicAdd(bcnt + tid*16, hist[tid]);   // padded 64B lines
  __syncthreads();
  for (int e = c0 + tid; e < c1; e += 256){
    int d = edst[e];
    int b = d >> 8;
    int p = gpos[b] + atomicAdd(&cur[b], 1);
    if (p < BCAP)
      bedge[(size_t)b*BCAP + p] = (unsigned)esrc[e] | ((unsigned)(d & 255) << 16);
  }
}

// ---------- CSR build phase 2: per-bucket LDS-cursor scatter ----------
// One wg per bucket; per-dst cursors live in LDS (zero global atomics).
// Writes slots[dst*CAP + pos] and cnt[dst] with plain stores.
__global__ __launch_bounds__(256) void k_bsort(
    const int* __restrict__ bcnt, const unsigned* __restrict__ bedge,
    int* __restrict__ cnt, unsigned short* __restrict__ slots, int N)
{
  __shared__ int cur[256];
  const int tid = threadIdx.x;
  const int b = blockIdx.x;
  cur[tid] = 0;
  __syncthreads();
  const int n = min(bcnt[b*16], BCAP);
  for (int i = tid; i < n; i += 256){
    unsigned e = bedge[(size_t)b*BCAP + i];
    int dl = e >> 16;
    int p = atomicAdd(&cur[dl], 1);
    if (p < CAP) slots[(size_t)(b*256 + dl)*CAP + p] = (unsigned short)(e & 0xFFFF);
  }
  __syncthreads();
  int dst = b*256 + tid;
  if (dst < N) cnt[dst] = cur[tid];
}

// ---------- linear: x@{Wq,Wk,Wv,Ws} + bias via MFMA ----------
// One block per 16-row strip, straight-line. Frag loads now coalesced.
__global__ __launch_bounds__(256) void k_linear4(
    const float* __restrict__ x, const short* __restrict__ fragw,
    const float* __restrict__ bq, const float* __restrict__ bk,
    const float* __restrict__ bv, const float* __restrict__ bs,
    float* __restrict__ q, __hip_bfloat16* __restrict__ kb,
    __hip_bfloat16* __restrict__ vb, float* __restrict__ sp, int N)
{
  const int lane = threadIdx.x & 63;
  const int w    = threadIdx.x >> 6;   // wave id = matrix id
  const int r16  = lane & 15;
  const int kg   = lane >> 4;

  const float* bm = (w==0) ? bq : (w==1) ? bk : (w==2) ? bv : bs;

  bf16x8 wh[4][2], wl[4][2];
  #pragma unroll
  for (int fi = 0; fi < 8; ++fi){
    wh[fi>>1][fi&1] = *(const bf16x8*)(fragw + ((size_t)(fi*2+0)*256 + w*64 + lane)*8);
    wl[fi>>1][fi&1] = *(const bf16x8*)(fragw + ((size_t)(fi*2+1)*256 + w*64 + lane)*8);
  }

  const int R0 = blockIdx.x << 4;
  const float* xp = x + (size_t)(R0 + r16)*D + 8*kg;
  float4 a0 = *(const float4*)(xp);        // k-half0: k=8kg+0..3
  float4 a1 = *(const float4*)(xp + 4);    //          k=8kg+4..7
  float4 a2 = *(const float4*)(xp + 32);   // k-half1
  float4 a3 = *(const float4*)(xp + 36);

  bf16x8 xh[2], xl[2];
  {
    float t;
    unsigned short hb;
    #define PK(kh, j, val) t=(val); hb=f2bu(t); xh[kh][j]=(short)hb; \
                           xl[kh][j]=(short)f2bu(t - b2f(hb));
    PK(0,0,a0.x) PK(0,1,a0.y) PK(0,2,a0.z) PK(0,3,a0.w)
    PK(0,4,a1.x) PK(0,5,a1.y) PK(0,6,a1.z) PK(0,7,a1.w)
    PK(1,0,a2.x) PK(1,1,a2.y) PK(1,2,a2.z) PK(1,3,a2.w)
    PK(1,4,a3.x) PK(1,5,a3.y) PK(1,6,a3.z) PK(1,7,a3.w)
    #undef PK
  }

  #pragma unroll
  for (int ct = 0; ct < 4; ++ct){
    float bv_ = bm[16*ct + r16];
    f32x4 acc = {bv_, bv_, bv_, bv_};
    #pragma unroll
    for (int kh = 0; kh < 2; ++kh){
      acc = __builtin_amdgcn_mfma_f32_16x16x32_bf16(xh[kh], wh[ct][kh], acc, 0,0,0);
      acc = __builtin_amdgcn_mfma_f32_16x16x32_bf16(xh[kh], wl[ct][kh], acc, 0,0,0);
      acc = __builtin_amdgcn_mfma_f32_16x16x32_bf16(xl[kh], wh[ct][kh], acc, 0,0,0);
    }
    #pragma unroll
    for (int i = 0; i < 4; ++i){
      size_t o = (size_t)(R0 + 4*kg + i)*D + 16*ct + r16;
      if (w == 0)      q[o] = acc[i];
      else if (w == 1) ((unsigned short*)kb)[o] = f2bu(acc[i]);
      else if (w == 2) ((unsigned short*)vb)[o] = f2bu(acc[i]);
      else             sp[o] = acc[i];
    }
  }
}

// ---------- fused attention gather: logits + softmax + PV + skip + ReLU ----------
__global__ __launch_bounds__(256) void k_attend(
    const float* __restrict__ q, const __hip_bfloat16* __restrict__ kb,
    const __hip_bfloat16* __restrict__ vb, float* __restrict__ sp,
    const int* __restrict__ cnt, const unsigned short* __restrict__ slots, int N)
{
  int node = blockIdx.x*4 + (threadIdx.x >> 6);
  if (node >= N) return;
  const int lane = threadIdx.x & 63;
  const int grp  = lane >> 4;
  const int gl   = lane & 15;

  float4 q4 = ((const float4*)(q + (size_t)node*D))[gl];
  int dg = min(cnt[node], CAP);
  int p0 = node*CAP;

  float den = 0.f;
  float ax=0.f, ay=0.f, az=0.f, aw=0.f;

  const unsigned short* ku = (const unsigned short*)kb;
  const unsigned short* vu = (const unsigned short*)vb;

  int sidx = (lane < dg) ? (int)slots[p0 + lane] : 0;   // dg <= CAP = 64
  int T = (dg + 3) >> 2;               // uniform trip count for all groups
  #pragma unroll 2
  for (int t = 0; t < T; ++t){
    int ei  = grp + 4*t;
    int eis = min(ei, dg - 1);         // clamped: always a valid source lane
    int s = __shfl(sidx, eis, 64);     // executed by all 64 lanes
    if (ei < dg){                      // group-uniform predicate
      ushort4 k4 = ((const ushort4*)(ku + (size_t)s*D))[gl];
      float p = q4.x*b2f(k4.x) + q4.y*b2f(k4.y)
              + q4.z*b2f(k4.z) + q4.w*b2f(k4.w);
      p = dppadd<0x121>(p);            // += row_ror:1
      p = dppadd<0x122>(p);            // += row_ror:2
      p = dppadd<0x124>(p);            // += row_ror:4
      p = dppadd<0x128>(p);            // += row_ror:8  -> 16-lane total
      float ex = __expf(fminf(p * 0.125f, 60.f));   // 1/sqrt(64)
      ushort4 v4 = ((const ushort4*)(vu + (size_t)s*D))[gl];
      den += ex;
      ax = fmaf(ex, b2f(v4.x), ax);
      ay = fmaf(ex, b2f(v4.y), ay);
      az = fmaf(ex, b2f(v4.z), az);
      aw = fmaf(ex, b2f(v4.w), aw);
    }
  }

  // merge the 4 groups (lanes gl, gl+16, gl+32, gl+48): plain sums
  #pragma unroll
  for (int off = 16; off <= 32; off <<= 1){
    den += __shfl_xor(den, off, 64);
    ax  += __shfl_xor(ax,  off, 64);
    ay  += __shfl_xor(ay,  off, 64);
    az  += __shfl_xor(az,  off, 64);
    aw  += __shfl_xor(aw,  off, 64);
  }

  if (grp == 0){
    float4 s4 = ((const float4*)(sp + (size_t)node*D))[gl];
    float4 o;
    if (dg > 0){
      float inv = 1.f/den;
      o.x = fmaf(ax, inv, s4.x);
      o.y = fmaf(ay, inv, s4.y);
      o.z = fmaf(az, inv, s4.z);
      o.w = fmaf(aw, inv, s4.w);
    } else {
      o = s4;
    }
    o.x = fmaxf(o.x, 0.f); o.y = fmaxf(o.y, 0.f);
    o.z = fmaxf(o.z, 0.f); o.w = fmaxf(o.w, 0.f);
    ((float4*)(sp + (size_t)node*D))[gl] = o;
  }
}

// ---------- mean pool: register accumulation per wave strip ----------
__global__ __launch_bounds__(256) void k_pool(
    const float* __restrict__ rows, const int* __restrict__ batch,
    float* __restrict__ gsum, float* __restrict__ gcnt, int N, int rpw)
{
  const int lane = threadIdx.x & 63;
  const int wid  = threadIdx.x >> 6;
  int wi = blockIdx.x*4 + wid;
  int start = wi * rpw;
  if (start >= N) return;
  int end = min(start + rpw, N);

  float acc = 0.f, c = 0.f;
  int gcur = batch[start];
  #pragma unroll 4
  for (int row = start; row < end; ++row){
    int g = batch[row];                     // wave-uniform scalar load
    float val = rows[(size_t)row*D + lane]; // coalesced 256B per wave
    if (g != gcur){
      atomicAdd(gsum + (size_t)gcur*D + lane, acc);
      if (lane == 0) atomicAdd(gcnt + gcur, c);
      acc = 0.f; c = 0.f; gcur = g;
    }
    acc += val;
    c += 1.f;
  }
  atomicAdd(gsum + (size_t)gcur*D + lane, acc);
  if (lane == 0) atomicAdd(gcnt + gcur, c);
}

__global__ __launch_bounds__(256) void k_final(
    const float* __restrict__ gsum, const float* __restrict__ gcnt,
    float* __restrict__ out, int n)
{
  int i = blockIdx.x*256 + threadIdx.x;
  if (i >= n) return;
  int g = i >> 6;
  out[i] = gsum[i] / fmaxf(gcnt[g], 1.0f);
}

extern "C" void kernel_launch(void* const* d_in, const int* in_sizes, int n_in,
                              void* d_out, int out_size, void* d_ws, size_t ws_size,
                              hipStream_t stream)
{
  const float* x   = (const float*)d_in[0];
  const int*  ei   = (const int*)d_in[1];
  const int*  batch= (const int*)d_in[2];
  const float* Wq  = (const float*)d_in[3];
  const float* bq  = (const float*)d_in[4];
  const float* Wk  = (const float*)d_in[5];
  const float* bk  = (const float*)d_in[6];
  const float* Wv  = (const float*)d_in[7];
  const float* bv  = (const float*)d_in[8];
  const float* Ws  = (const float*)d_in[9];
  const float* bs  = (const float*)d_in[10];
  float* out = (float*)d_out;

  const int N = in_sizes[0] / D;   // 50000
  const int E = in_sizes[1] / 2;   // 800000
  const int* esrc = ei;
  const int* edst = ei + E;

  float* ws = (float*)d_ws;
  size_t off = 0;
  float* q    = ws + off; off += (size_t)N*D;
  __hip_bfloat16* kb = (__hip_bfloat16*)(ws + off); off += (size_t)N*D/2;
  __hip_bfloat16* vb = (__hip_bfloat16*)(ws + off); off += (size_t)N*D/2;
  float* sp   = ws + off; off += (size_t)N*D;   // s-proj in, relu(out) in-place
  // zero region: [bcnt (padded, 1 int per 64B line) | gsum | gcnt]
  int*   bcnt = (int*)(ws + off);  off += (size_t)NB*16;
  float* gsum = ws + off; off += (size_t)NG*D;
  float* gcnt = ws + off; off += NG;
  int*   cnt  = (int*)(ws + off);  off += N;            // written by k_bsort
  unsigned* bedge = (unsigned*)(ws + off); off += (size_t)NB*BCAP;
  unsigned short* slots = (unsigned short*)(ws + off); off += (size_t)N*CAP/2;
  short* fragw = (short*)(ws + off); off += 16*256*8/2;  // 64 KB

  size_t zbytes = ((size_t)NB*16 + (size_t)NG*D + NG) * sizeof(float);
  hipMemsetAsync((void*)bcnt, 0, zbytes, stream);

  const int nChunk = (E + 255) / 256;   // 3125

  k_wprep  <<<8, 256, 0, stream>>>(Wq, Wk, Wv, Ws, fragw);
  k_split  <<<256, 256, 0, stream>>>(esrc, edst, bcnt, bedge, E, nChunk);
  k_bsort  <<<NB, 256, 0, stream>>>(bcnt, bedge, cnt, slots, N);
  k_linear4<<<N/16, 256, 0, stream>>>(x, fragw, bq, bk, bv, bs,
                                      q, kb, vb, sp, N);
  k_attend <<<(N+3)/4, 256, 0, stream>>>(q, kb, vb, sp, cnt, slots, N);
  const int rpw = 32;
  int nwaves = (N + rpw - 1) / rpw;
  k_pool <<<(nwaves+3)/4, 256, 0, stream>>>(sp, batch, gsum, gcnt, N, rpw);
  k_final<<<(NG*D+255)/256, 256, 0, stream>>>(gsum, gcnt, out, NG*D);
}

// Round 16
// 113.220 us; speedup vs baseline: 1.3688x; 1.0423x over previous
//
#include <hip/hip_runtime.h>
#include <hip/hip_bf16.h>

#define D 64
#define NG 64
#define CAP 64      // per-node slot capacity (Poisson(16); P(>64)~1e-17)
#define NB 196      // dst buckets: bucket = dst>>8 (49999>>8 = 195)
#define BCAP 5120   // per-bucket edge capacity (mean 4096, +16 sigma)

typedef short bf16x8 __attribute__((ext_vector_type(8)));
typedef float f32x4  __attribute__((ext_vector_type(4)));
typedef unsigned short u16x8 __attribute__((ext_vector_type(8)));

__device__ __forceinline__ float b2f(unsigned short u){
  return __uint_as_float(((unsigned)u) << 16);
}
__device__ __forceinline__ unsigned short f2bu(float f){
  return __builtin_bit_cast(unsigned short, __float2bfloat16(f));
}

// VALU-pipe cross-lane add: x += dpp_perm<C>(x)
template<int C>
__device__ __forceinline__ float dppadd(float x){
  int t = __builtin_amdgcn_update_dpp(0, __float_as_int(x), C, 0xf, 0xf, true);
  return x + __int_as_float(t);
}

// ---------- pass 0: W-fragment precompute + zero-init (8 blocks) ----------
// Also zeroes [bcnt|gsum|gcnt] so NO hipMemsetAsync sits in the graph.
__global__ __launch_bounds__(256) void k_wprep(
    const float* __restrict__ Wq, const float* __restrict__ Wk,
    const float* __restrict__ Wv, const float* __restrict__ Ws,
    short* __restrict__ fragw, int* __restrict__ zptr, int zn)
{
  for (int i = blockIdx.x*256 + threadIdx.x; i < zn; i += 8*256) zptr[i] = 0;

  const int m    = blockIdx.x >> 1;
  const int kh   = blockIdx.x & 1;
  const int ct   = threadIdx.x >> 6;
  const int lane = threadIdx.x & 63;
  const int r16  = lane & 15;
  const int kg   = lane >> 4;
  const float* Wm = (m==0) ? Wq : (m==1) ? Wk : (m==2) ? Wv : Ws;
  bf16x8 hi, lo;
  #pragma unroll
  for (int j = 0; j < 8; ++j){
    float wv = Wm[(32*kh + 8*kg + j)*D + 16*ct + r16];
    unsigned short hb = f2bu(wv);
    hi[j] = (short)hb;
    lo[j] = (short)f2bu(wv - b2f(hb));
  }
  int fi = ct*2 + kh;
  *(bf16x8*)(fragw + ((size_t)(fi*2+0)*256 + m*64 + lane)*8) = hi;
  *(bf16x8*)(fragw + ((size_t)(fi*2+1)*256 + m*64 + lane)*8) = lo;
}

// ---------- CSR build phase 1: LDS multisplit into dst-range buckets --------
__global__ __launch_bounds__(256) void k_split(
    const int* __restrict__ esrc, const int* __restrict__ edst,
    int* __restrict__ bcnt, unsigned* __restrict__ bedge, int E, int nChunk)
{
  __shared__ int hist[NB], gpos[NB], cur[NB];
  const int tid = threadIdx.x;
  if (tid < NB){ hist[tid] = 0; cur[tid] = 0; }
  __syncthreads();
  const int c0 = blockIdx.x * nChunk;
  const int c1 = min(c0 + nChunk, E);
  for (int e = c0 + tid; e < c1; e += 256)
    atomicAdd(&hist[edst[e] >> 8], 1);
  __syncthreads();
  if (tid < NB && hist[tid] > 0)
    gpos[tid] = atomicAdd(bcnt + tid*16, hist[tid]);   // padded 64B lines
  __syncthreads();
  for (int e = c0 + tid; e < c1; e += 256){
    int d = edst[e];
    int b = d >> 8;
    int p = gpos[b] + atomicAdd(&cur[b], 1);
    if (p < BCAP)
      bedge[(size_t)b*BCAP + p] = (unsigned)esrc[e] | ((unsigned)(d & 255) << 16);
  }
}

// ---------- CSR build phase 2: per-bucket LDS-cursor scatter ----------
__global__ __launch_bounds__(256) void k_bsort(
    const int* __restrict__ bcnt, const unsigned* __restrict__ bedge,
    int* __restrict__ cnt, unsigned short* __restrict__ slots, int N)
{
  __shared__ int cur[256];
  const int tid = threadIdx.x;
  const int b = blockIdx.x;
  cur[tid] = 0;
  __syncthreads();
  const int n = min(bcnt[b*16], BCAP);
  for (int i = tid; i < n; i += 256){
    unsigned e = bedge[(size_t)b*BCAP + i];
    int dl = e >> 16;
    int p = atomicAdd(&cur[dl], 1);
    if (p < CAP) slots[(size_t)(b*256 + dl)*CAP + p] = (unsigned short)(e & 0xFFFF);
  }
  __syncthreads();
  int dst = b*256 + tid;
  if (dst < N) cnt[dst] = cur[tid];
}

// ---------- linear: x@{Wq,Wk,Wv,Ws} + bias via MFMA ----------
__global__ __launch_bounds__(256) void k_linear4(
    const float* __restrict__ x, const short* __restrict__ fragw,
    const float* __restrict__ bq, const float* __restrict__ bk,
    const float* __restrict__ bv, const float* __restrict__ bs,
    float* __restrict__ q, __hip_bfloat16* __restrict__ kb,
    __hip_bfloat16* __restrict__ vb, float* __restrict__ sp, int N)
{
  const int lane = threadIdx.x & 63;
  const int w    = threadIdx.x >> 6;   // wave id = matrix id
  const int r16  = lane & 15;
  const int kg   = lane >> 4;

  const float* bm = (w==0) ? bq : (w==1) ? bk : (w==2) ? bv : bs;

  bf16x8 wh[4][2], wl[4][2];
  #pragma unroll
  for (int fi = 0; fi < 8; ++fi){
    wh[fi>>1][fi&1] = *(const bf16x8*)(fragw + ((size_t)(fi*2+0)*256 + w*64 + lane)*8);
    wl[fi>>1][fi&1] = *(const bf16x8*)(fragw + ((size_t)(fi*2+1)*256 + w*64 + lane)*8);
  }

  const int R0 = blockIdx.x << 4;
  const float* xp = x + (size_t)(R0 + r16)*D + 8*kg;
  float4 a0 = *(const float4*)(xp);        // k-half0: k=8kg+0..3
  float4 a1 = *(const float4*)(xp + 4);    //          k=8kg+4..7
  float4 a2 = *(const float4*)(xp + 32);   // k-half1
  float4 a3 = *(const float4*)(xp + 36);

  bf16x8 xh[2], xl[2];
  {
    float t;
    unsigned short hb;
    #define PK(kh, j, val) t=(val); hb=f2bu(t); xh[kh][j]=(short)hb; \
                           xl[kh][j]=(short)f2bu(t - b2f(hb));
    PK(0,0,a0.x) PK(0,1,a0.y) PK(0,2,a0.z) PK(0,3,a0.w)
    PK(0,4,a1.x) PK(0,5,a1.y) PK(0,6,a1.z) PK(0,7,a1.w)
    PK(1,0,a2.x) PK(1,1,a2.y) PK(1,2,a2.z) PK(1,3,a2.w)
    PK(1,4,a3.x) PK(1,5,a3.y) PK(1,6,a3.z) PK(1,7,a3.w)
    #undef PK
  }

  #pragma unroll
  for (int ct = 0; ct < 4; ++ct){
    float bv_ = bm[16*ct + r16];
    f32x4 acc = {bv_, bv_, bv_, bv_};
    #pragma unroll
    for (int kh = 0; kh < 2; ++kh){
      acc = __builtin_amdgcn_mfma_f32_16x16x32_bf16(xh[kh], wh[ct][kh], acc, 0,0,0);
      acc = __builtin_amdgcn_mfma_f32_16x16x32_bf16(xh[kh], wl[ct][kh], acc, 0,0,0);
      acc = __builtin_amdgcn_mfma_f32_16x16x32_bf16(xl[kh], wh[ct][kh], acc, 0,0,0);
    }
    #pragma unroll
    for (int i = 0; i < 4; ++i){
      size_t o = (size_t)(R0 + 4*kg + i)*D + 16*ct + r16;
      if (w == 0)      q[o] = acc[i];
      else if (w == 1) ((unsigned short*)kb)[o] = f2bu(acc[i]);
      else if (w == 2) ((unsigned short*)vb)[o] = f2bu(acc[i]);
      else             sp[o] = acc[i];
    }
  }
}

// ---------- fused attention gather: logits + softmax + PV + skip + ReLU -----
// 8 groups x 8 lanes per wave: 8 edges in flight, k/v rows read as ushort8
// (16B/lane, half the requests of the 16-lane layout). Dot-reduce over the
// 8-lane group entirely on the DPP pipe: quad_perm xor1 (0xB1), xor2 (0x4E),
// then row_half_mirror (0x141 — valid for a sum: both quads hold quad-totals).
__global__ __launch_bounds__(256) void k_attend(
    const float* __restrict__ q, const __hip_bfloat16* __restrict__ kb,
    const __hip_bfloat16* __restrict__ vb, float* __restrict__ sp,
    const int* __restrict__ cnt, const unsigned short* __restrict__ slots, int N)
{
  int node = blockIdx.x*4 + (threadIdx.x >> 6);
  if (node >= N) return;
  const int lane = threadIdx.x & 63;
  const int grp  = lane >> 3;   // 8 groups
  const int gl   = lane & 7;    // 8 lanes/group; lane gl owns dims [8gl,8gl+8)

  const float4* qp = (const float4*)(q + (size_t)node*D);
  float4 qa = qp[2*gl], qb = qp[2*gl+1];

  int dg = min(cnt[node], CAP);
  int p0 = node*CAP;

  float den = 0.f;
  float4 aa = {0,0,0,0}, ab = {0,0,0,0};

  const unsigned short* ku = (const unsigned short*)kb;
  const unsigned short* vu = (const unsigned short*)vb;

  int sidx = (lane < dg) ? (int)slots[p0 + lane] : 0;   // dg <= CAP = 64
  int T = (dg + 7) >> 3;               // uniform trip count for all groups
  #pragma unroll 2
  for (int t = 0; t < T; ++t){
    int ei  = grp + 8*t;
    int eis = min(ei, dg - 1);         // clamped: always a valid source lane
    int s = __shfl(sidx, eis, 64);     // executed by all 64 lanes
    if (ei < dg){                      // group-uniform predicate
      u16x8 k8 = *(const u16x8*)(ku + (size_t)s*D + 8*gl);
      float p = qa.x*b2f(k8[0]) + qa.y*b2f(k8[1])
              + qa.z*b2f(k8[2]) + qa.w*b2f(k8[3])
              + qb.x*b2f(k8[4]) + qb.y*b2f(k8[5])
              + qb.z*b2f(k8[6]) + qb.w*b2f(k8[7]);
      p = dppadd<0xB1>(p);             // quad_perm [1,0,3,2]  : += xor1
      p = dppadd<0x4E>(p);             // quad_perm [2,3,0,1]  : += xor2
      p = dppadd<0x141>(p);            // row_half_mirror      : += other quad
      float ex = __expf(fminf(p * 0.125f, 60.f));   // 1/sqrt(64)
      u16x8 v8 = *(const u16x8*)(vu + (size_t)s*D + 8*gl);
      den += ex;
      aa.x = fmaf(ex, b2f(v8[0]), aa.x);
      aa.y = fmaf(ex, b2f(v8[1]), aa.y);
      aa.z = fmaf(ex, b2f(v8[2]), aa.z);
      aa.w = fmaf(ex, b2f(v8[3]), aa.w);
      ab.x = fmaf(ex, b2f(v8[4]), ab.x);
      ab.y = fmaf(ex, b2f(v8[5]), ab.y);
      ab.z = fmaf(ex, b2f(v8[6]), ab.z);
      ab.w = fmaf(ex, b2f(v8[7]), ab.w);
    }
  }

  // merge the 8 groups: row_ror:8 (pairs groups within each 16-lane row),
  // then shfl_xor 16 and 32. All lanes active here.
  #define MRG(v) v = dppadd<0x128>(v); \
                 v += __shfl_xor(v, 16, 64); \
                 v += __shfl_xor(v, 32, 64);
  MRG(den)
  MRG(aa.x) MRG(aa.y) MRG(aa.z) MRG(aa.w)
  MRG(ab.x) MRG(ab.y) MRG(ab.z) MRG(ab.w)
  #undef MRG

  if (grp == 0){   // lanes 0..7 hold the full row; lane gl stores dims [8gl,8gl+8)
    float4* spp = (float4*)(sp + (size_t)node*D);
    float4 s4a = spp[2*gl], s4b = spp[2*gl+1];
    float4 oa, ob;
    if (dg > 0){
      float inv = 1.f/den;
      oa.x = fmaf(aa.x, inv, s4a.x); oa.y = fmaf(aa.y, inv, s4a.y);
      oa.z = fmaf(aa.z, inv, s4a.z); oa.w = fmaf(aa.w, inv, s4a.w);
      ob.x = fmaf(ab.x, inv, s4b.x); ob.y = fmaf(ab.y, inv, s4b.y);
      ob.z = fmaf(ab.z, inv, s4b.z); ob.w = fmaf(ab.w, inv, s4b.w);
    } else {
      oa = s4a; ob = s4b;
    }
    oa.x = fmaxf(oa.x, 0.f); oa.y = fmaxf(oa.y, 0.f);
    oa.z = fmaxf(oa.z, 0.f); oa.w = fmaxf(oa.w, 0.f);
    ob.x = fmaxf(ob.x, 0.f); ob.y = fmaxf(ob.y, 0.f);
    ob.z = fmaxf(ob.z, 0.f); ob.w = fmaxf(ob.w, 0.f);
    spp[2*gl]   = oa;
    spp[2*gl+1] = ob;
  }
}

// ---------- mean pool: register accumulation per wave strip ----------
__global__ __launch_bounds__(256) void k_pool(
    const float* __restrict__ rows, const int* __restrict__ batch,
    float* __restrict__ gsum, float* __restrict__ gcnt, int N, int rpw)
{
  const int lane = threadIdx.x & 63;
  const int wid  = threadIdx.x >> 6;
  int wi = blockIdx.x*4 + wid;
  int start = wi * rpw;
  if (start >= N) return;
  int end = min(start + rpw, N);

  float acc = 0.f, c = 0.f;
  int gcur = batch[start];
  #pragma unroll 4
  for (int row = start; row < end; ++row){
    int g = batch[row];                     // wave-uniform scalar load
    float val = rows[(size_t)row*D + lane]; // coalesced 256B per wave
    if (g != gcur){
      atomicAdd(gsum + (size_t)gcur*D + lane, acc);
      if (lane == 0) atomicAdd(gcnt + gcur, c);
      acc = 0.f; c = 0.f; gcur = g;
    }
    acc += val;
    c += 1.f;
  }
  atomicAdd(gsum + (size_t)gcur*D + lane, acc);
  if (lane == 0) atomicAdd(gcnt + gcur, c);
}

__global__ __launch_bounds__(256) void k_final(
    const float* __restrict__ gsum, const float* __restrict__ gcnt,
    float* __restrict__ out, int n)
{
  int i = blockIdx.x*256 + threadIdx.x;
  if (i >= n) return;
  int g = i >> 6;
  out[i] = gsum[i] / fmaxf(gcnt[g], 1.0f);
}

extern "C" void kernel_launch(void* const* d_in, const int* in_sizes, int n_in,
                              void* d_out, int out_size, void* d_ws, size_t ws_size,
                              hipStream_t stream)
{
  const float* x   = (const float*)d_in[0];
  const int*  ei   = (const int*)d_in[1];
  const int*  batch= (const int*)d_in[2];
  const float* Wq  = (const float*)d_in[3];
  const float* bq  = (const float*)d_in[4];
  const float* Wk  = (const float*)d_in[5];
  const float* bk  = (const float*)d_in[6];
  const float* Wv  = (const float*)d_in[7];
  const float* bv  = (const float*)d_in[8];
  const float* Ws  = (const float*)d_in[9];
  const float* bs  = (const float*)d_in[10];
  float* out = (float*)d_out;

  const int N = in_sizes[0] / D;   // 50000
  const int E = in_sizes[1] / 2;   // 800000
  const int* esrc = ei;
  const int* edst = ei + E;

  float* ws = (float*)d_ws;
  size_t off = 0;
  float* q    = ws + off; off += (size_t)N*D;
  __hip_bfloat16* kb = (__hip_bfloat16*)(ws + off); off += (size_t)N*D/2;
  __hip_bfloat16* vb = (__hip_bfloat16*)(ws + off); off += (size_t)N*D/2;
  float* sp   = ws + off; off += (size_t)N*D;   // s-proj in, relu(out) in-place
  // zero region (cleared by k_wprep): [bcnt | gsum | gcnt]
  int*   bcnt = (int*)(ws + off);  off += (size_t)NB*16;
  float* gsum = ws + off; off += (size_t)NG*D;
  float* gcnt = ws + off; off += NG;
  int*   cnt  = (int*)(ws + off);  off += N;            // fully written by k_bsort
  unsigned* bedge = (unsigned*)(ws + off); off += (size_t)NB*BCAP;
  unsigned short* slots = (unsigned short*)(ws + off); off += (size_t)N*CAP/2;
  short* fragw = (short*)(ws + off); off += 16*256*8/2;  // 64 KB

  const int zn = NB*16 + NG*D + NG;    // ints to zero (bcnt|gsum|gcnt)
  const int nChunk = (E + 255) / 256;  // 3125

  k_wprep  <<<8, 256, 0, stream>>>(Wq, Wk, Wv, Ws, fragw, bcnt, zn);
  k_split  <<<256, 256, 0, stream>>>(esrc, edst, bcnt, bedge, E, nChunk);
  k_bsort  <<<NB, 256, 0, stream>>>(bcnt, bedge, cnt, slots, N);
  k_linear4<<<N/16, 256, 0, stream>>>(x, fragw, bq, bk, bv, bs,
                                      q, kb, vb, sp, N);
  k_attend <<<(N+3)/4, 256, 0, stream>>>(q, kb, vb, sp, cnt, slots, N);
  const int rpw = 32;
  int nwaves = (N + rpw - 1) / rpw;
  k_pool <<<(nwaves+3)/4, 256, 0, stream>>>(sp, batch, gsum, gcnt, N, rpw);
  k_final<<<(NG*D+255)/256, 256, 0, stream>>>(gsum, gcnt, out, NG*D);
}

// Round 17
// 102.161 us; speedup vs baseline: 1.5170x; 1.1082x over previous
//
#include <hip/hip_runtime.h>
#include <hip/hip_bf16.h>

#define D 64
#define NG 64
#define CAP 64      // per-node slot capacity (Poisson(16); P(>64)~1e-17)
#define NB 196      // dst buckets: bucket = dst>>8 (49999>>8 = 195)
#define BCAP 5120   // per-bucket edge capacity (mean 4096, +16 sigma)

typedef short bf16x8 __attribute__((ext_vector_type(8)));
typedef float f32x4  __attribute__((ext_vector_type(4)));
typedef unsigned short u16x8 __attribute__((ext_vector_type(8)));

__device__ __forceinline__ float b2f(unsigned short u){
  return __uint_as_float(((unsigned)u) << 16);
}
__device__ __forceinline__ unsigned short f2bu(float f){
  return __builtin_bit_cast(unsigned short, __float2bfloat16(f));
}

// VALU-pipe cross-lane add: x += dpp_perm<C>(x)
template<int C>
__device__ __forceinline__ float dppadd(float x){
  int t = __builtin_amdgcn_update_dpp(0, __float_as_int(x), C, 0xf, 0xf, true);
  return x + __int_as_float(t);
}

// ---------- pass 0: W-fragment precompute + zero-init (8 blocks) ----------
__global__ __launch_bounds__(256) void k_wprep(
    const float* __restrict__ Wq, const float* __restrict__ Wk,
    const float* __restrict__ Wv, const float* __restrict__ Ws,
    short* __restrict__ fragw, int* __restrict__ zptr, int zn)
{
  for (int i = blockIdx.x*256 + threadIdx.x; i < zn; i += 8*256) zptr[i] = 0;

  const int m    = blockIdx.x >> 1;
  const int kh   = blockIdx.x & 1;
  const int ct   = threadIdx.x >> 6;
  const int lane = threadIdx.x & 63;
  const int r16  = lane & 15;
  const int kg   = lane >> 4;
  const float* Wm = (m==0) ? Wq : (m==1) ? Wk : (m==2) ? Wv : Ws;
  bf16x8 hi, lo;
  #pragma unroll
  for (int j = 0; j < 8; ++j){
    float wv = Wm[(32*kh + 8*kg + j)*D + 16*ct + r16];
    unsigned short hb = f2bu(wv);
    hi[j] = (short)hb;
    lo[j] = (short)f2bu(wv - b2f(hb));
  }
  int fi = ct*2 + kh;
  *(bf16x8*)(fragw + ((size_t)(fi*2+0)*256 + m*64 + lane)*8) = hi;
  *(bf16x8*)(fragw + ((size_t)(fi*2+1)*256 + m*64 + lane)*8) = lo;
}

// ---------- fused: LDS multisplit (blocks 0..nSplit-1)  ||  MFMA linear -----
// Independent dep-chains (split needs only edge_index; linear needs x+fragw).
// Split is LDS-atomic based (no global atomic storm), so the two genuinely
// share the machine: split blocks seize CUs first, linear fills the rest.
// Linear handles 2 strips/block to amortize the 16-load fragment preamble.
__global__ __launch_bounds__(256) void k_fused(
    const int* __restrict__ esrc, const int* __restrict__ edst,
    int* __restrict__ bcnt, unsigned* __restrict__ bedge, int E, int nChunk,
    int nSplit,
    const float* __restrict__ x, const short* __restrict__ fragw,
    const float* __restrict__ bq, const float* __restrict__ bk,
    const float* __restrict__ bv, const float* __restrict__ bs,
    float* __restrict__ q, __hip_bfloat16* __restrict__ kb,
    __hip_bfloat16* __restrict__ vb, float* __restrict__ sp, int N)
{
  __shared__ int hist[NB], gpos[NB], cur[NB];

  if ((int)blockIdx.x < nSplit){
    const int tid = threadIdx.x;
    if (tid < NB){ hist[tid] = 0; cur[tid] = 0; }
    __syncthreads();
    const int c0 = blockIdx.x * nChunk;
    const int c1 = min(c0 + nChunk, E);
    for (int e = c0 + tid; e < c1; e += 256)
      atomicAdd(&hist[edst[e] >> 8], 1);
    __syncthreads();
    if (tid < NB && hist[tid] > 0)
      gpos[tid] = atomicAdd(bcnt + tid*16, hist[tid]);   // padded 64B lines
    __syncthreads();
    for (int e = c0 + tid; e < c1; e += 256){
      int d = edst[e];
      int b = d >> 8;
      int p = gpos[b] + atomicAdd(&cur[b], 1);
      if (p < BCAP)
        bedge[(size_t)b*BCAP + p] = (unsigned)esrc[e] | ((unsigned)(d & 255) << 16);
    }
    return;
  }

  // ---- linear: 2 strips of 16 rows per block ----
  const int lane = threadIdx.x & 63;
  const int w    = threadIdx.x >> 6;   // wave id = matrix id
  const int r16  = lane & 15;
  const int kg   = lane >> 4;

  const float* bm = (w==0) ? bq : (w==1) ? bk : (w==2) ? bv : bs;

  bf16x8 wh[4][2], wl[4][2];
  #pragma unroll
  for (int fi = 0; fi < 8; ++fi){
    wh[fi>>1][fi&1] = *(const bf16x8*)(fragw + ((size_t)(fi*2+0)*256 + w*64 + lane)*8);
    wl[fi>>1][fi&1] = *(const bf16x8*)(fragw + ((size_t)(fi*2+1)*256 + w*64 + lane)*8);
  }
  float bias[4];
  #pragma unroll
  for (int ct = 0; ct < 4; ++ct) bias[ct] = bm[16*ct + r16];

  const int nStrip = N >> 4;   // 3125
  const int s0 = (blockIdx.x - nSplit) * 2;
  #pragma unroll
  for (int it = 0; it < 2; ++it){
    const int strip = s0 + it;
    if (strip >= nStrip) break;
    const int R0 = strip << 4;
    const float* xp = x + (size_t)(R0 + r16)*D + 8*kg;
    float4 a0 = *(const float4*)(xp);        // k-half0: k=8kg+0..3
    float4 a1 = *(const float4*)(xp + 4);    //          k=8kg+4..7
    float4 a2 = *(const float4*)(xp + 32);   // k-half1
    float4 a3 = *(const float4*)(xp + 36);

    bf16x8 xh[2], xl[2];
    {
      float t;
      unsigned short hb;
      #define PK(kh, j, val) t=(val); hb=f2bu(t); xh[kh][j]=(short)hb; \
                             xl[kh][j]=(short)f2bu(t - b2f(hb));
      PK(0,0,a0.x) PK(0,1,a0.y) PK(0,2,a0.z) PK(0,3,a0.w)
      PK(0,4,a1.x) PK(0,5,a1.y) PK(0,6,a1.z) PK(0,7,a1.w)
      PK(1,0,a2.x) PK(1,1,a2.y) PK(1,2,a2.z) PK(1,3,a2.w)
      PK(1,4,a3.x) PK(1,5,a3.y) PK(1,6,a3.z) PK(1,7,a3.w)
      #undef PK
    }

    #pragma unroll
    for (int ct = 0; ct < 4; ++ct){
      f32x4 acc = {bias[ct], bias[ct], bias[ct], bias[ct]};
      #pragma unroll
      for (int kh = 0; kh < 2; ++kh){
        acc = __builtin_amdgcn_mfma_f32_16x16x32_bf16(xh[kh], wh[ct][kh], acc, 0,0,0);
        acc = __builtin_amdgcn_mfma_f32_16x16x32_bf16(xh[kh], wl[ct][kh], acc, 0,0,0);
        acc = __builtin_amdgcn_mfma_f32_16x16x32_bf16(xl[kh], wh[ct][kh], acc, 0,0,0);
      }
      #pragma unroll
      for (int i = 0; i < 4; ++i){
        size_t o = (size_t)(R0 + 4*kg + i)*D + 16*ct + r16;
        if (w == 0)      q[o] = acc[i];
        else if (w == 1) ((unsigned short*)kb)[o] = f2bu(acc[i]);
        else if (w == 2) ((unsigned short*)vb)[o] = f2bu(acc[i]);
        else             sp[o] = acc[i];
      }
    }
  }
}

// ---------- CSR build phase 2: per-bucket LDS-cursor scatter ----------
__global__ __launch_bounds__(256) void k_bsort(
    const int* __restrict__ bcnt, const unsigned* __restrict__ bedge,
    int* __restrict__ cnt, unsigned short* __restrict__ slots, int N)
{
  __shared__ int cur[256];
  const int tid = threadIdx.x;
  const int b = blockIdx.x;
  cur[tid] = 0;
  __syncthreads();
  const int n = min(bcnt[b*16], BCAP);
  for (int i = tid; i < n; i += 256){
    unsigned e = bedge[(size_t)b*BCAP + i];
    int dl = e >> 16;
    int p = atomicAdd(&cur[dl], 1);
    if (p < CAP) slots[(size_t)(b*256 + dl)*CAP + p] = (unsigned short)(e & 0xFFFF);
  }
  __syncthreads();
  int dst = b*256 + tid;
  if (dst < N) cnt[dst] = cur[tid];
}

// ---------- fused attention gather: logits + softmax + PV + skip + ReLU -----
// 8 groups x 8 lanes per wave: 8 edges in flight, k/v rows read as ushort8.
__global__ __launch_bounds__(256) void k_attend(
    const float* __restrict__ q, const __hip_bfloat16* __restrict__ kb,
    const __hip_bfloat16* __restrict__ vb, float* __restrict__ sp,
    const int* __restrict__ cnt, const unsigned short* __restrict__ slots, int N)
{
  int node = blockIdx.x*4 + (threadIdx.x >> 6);
  if (node >= N) return;
  const int lane = threadIdx.x & 63;
  const int grp  = lane >> 3;   // 8 groups
  const int gl   = lane & 7;    // 8 lanes/group; lane gl owns dims [8gl,8gl+8)

  const float4* qp = (const float4*)(q + (size_t)node*D);
  float4 qa = qp[2*gl], qb = qp[2*gl+1];

  int dg = min(cnt[node], CAP);
  int p0 = node*CAP;

  float den = 0.f;
  float4 aa = {0,0,0,0}, ab = {0,0,0,0};

  const unsigned short* ku = (const unsigned short*)kb;
  const unsigned short* vu = (const unsigned short*)vb;

  int sidx = (lane < dg) ? (int)slots[p0 + lane] : 0;   // dg <= CAP = 64
  int T = (dg + 7) >> 3;               // uniform trip count for all groups
  #pragma unroll 2
  for (int t = 0; t < T; ++t){
    int ei  = grp + 8*t;
    int eis = min(ei, dg - 1);         // clamped: always a valid source lane
    int s = __shfl(sidx, eis, 64);     // executed by all 64 lanes
    if (ei < dg){                      // group-uniform predicate
      u16x8 k8 = *(const u16x8*)(ku + (size_t)s*D + 8*gl);
      float p = qa.x*b2f(k8[0]) + qa.y*b2f(k8[1])
              + qa.z*b2f(k8[2]) + qa.w*b2f(k8[3])
              + qb.x*b2f(k8[4]) + qb.y*b2f(k8[5])
              + qb.z*b2f(k8[6]) + qb.w*b2f(k8[7]);
      p = dppadd<0xB1>(p);             // quad_perm [1,0,3,2]  : += xor1
      p = dppadd<0x4E>(p);             // quad_perm [2,3,0,1]  : += xor2
      p = dppadd<0x141>(p);            // row_half_mirror      : += other quad
      float ex = __expf(fminf(p * 0.125f, 60.f));   // 1/sqrt(64)
      u16x8 v8 = *(const u16x8*)(vu + (size_t)s*D + 8*gl);
      den += ex;
      aa.x = fmaf(ex, b2f(v8[0]), aa.x);
      aa.y = fmaf(ex, b2f(v8[1]), aa.y);
      aa.z = fmaf(ex, b2f(v8[2]), aa.z);
      aa.w = fmaf(ex, b2f(v8[3]), aa.w);
      ab.x = fmaf(ex, b2f(v8[4]), ab.x);
      ab.y = fmaf(ex, b2f(v8[5]), ab.y);
      ab.z = fmaf(ex, b2f(v8[6]), ab.z);
      ab.w = fmaf(ex, b2f(v8[7]), ab.w);
    }
  }

  // merge the 8 groups: row_ror:8, then shfl_xor 16 and 32 (all lanes active)
  #define MRG(v) v = dppadd<0x128>(v); \
                 v += __shfl_xor(v, 16, 64); \
                 v += __shfl_xor(v, 32, 64);
  MRG(den)
  MRG(aa.x) MRG(aa.y) MRG(aa.z) MRG(aa.w)
  MRG(ab.x) MRG(ab.y) MRG(ab.z) MRG(ab.w)
  #undef MRG

  if (grp == 0){   // lanes 0..7 hold the full row; lane gl stores dims [8gl,8gl+8)
    float4* spp = (float4*)(sp + (size_t)node*D);
    float4 s4a = spp[2*gl], s4b = spp[2*gl+1];
    float4 oa, ob;
    if (dg > 0){
      float inv = 1.f/den;
      oa.x = fmaf(aa.x, inv, s4a.x); oa.y = fmaf(aa.y, inv, s4a.y);
      oa.z = fmaf(aa.z, inv, s4a.z); oa.w = fmaf(aa.w, inv, s4a.w);
      ob.x = fmaf(ab.x, inv, s4b.x); ob.y = fmaf(ab.y, inv, s4b.y);
      ob.z = fmaf(ab.z, inv, s4b.z); ob.w = fmaf(ab.w, inv, s4b.w);
    } else {
      oa = s4a; ob = s4b;
    }
    oa.x = fmaxf(oa.x, 0.f); oa.y = fmaxf(oa.y, 0.f);
    oa.z = fmaxf(oa.z, 0.f); oa.w = fmaxf(oa.w, 0.f);
    ob.x = fmaxf(ob.x, 0.f); ob.y = fmaxf(ob.y, 0.f);
    ob.z = fmaxf(ob.z, 0.f); ob.w = fmaxf(ob.w, 0.f);
    spp[2*gl]   = oa;
    spp[2*gl+1] = ob;
  }
}

// ---------- mean pool: register accumulation per wave strip ----------
__global__ __launch_bounds__(256) void k_pool(
    const float* __restrict__ rows, const int* __restrict__ batch,
    float* __restrict__ gsum, float* __restrict__ gcnt, int N, int rpw)
{
  const int lane = threadIdx.x & 63;
  const int wid  = threadIdx.x >> 6;
  int wi = blockIdx.x*4 + wid;
  int start = wi * rpw;
  if (start >= N) return;
  int end = min(start + rpw, N);

  float acc = 0.f, c = 0.f;
  int gcur = batch[start];
  #pragma unroll 4
  for (int row = start; row < end; ++row){
    int g = batch[row];                     // wave-uniform scalar load
    float val = rows[(size_t)row*D + lane]; // coalesced 256B per wave
    if (g != gcur){
      atomicAdd(gsum + (size_t)gcur*D + lane, acc);
      if (lane == 0) atomicAdd(gcnt + gcur, c);
      acc = 0.f; c = 0.f; gcur = g;
    }
    acc += val;
    c += 1.f;
  }
  atomicAdd(gsum + (size_t)gcur*D + lane, acc);
  if (lane == 0) atomicAdd(gcnt + gcur, c);
}

__global__ __launch_bounds__(256) void k_final(
    const float* __restrict__ gsum, const float* __restrict__ gcnt,
    float* __restrict__ out, int n)
{
  int i = blockIdx.x*256 + threadIdx.x;
  if (i >= n) return;
  int g = i >> 6;
  out[i] = gsum[i] / fmaxf(gcnt[g], 1.0f);
}

extern "C" void kernel_launch(void* const* d_in, const int* in_sizes, int n_in,
                              void* d_out, int out_size, void* d_ws, size_t ws_size,
                              hipStream_t stream)
{
  const float* x   = (const float*)d_in[0];
  const int*  ei   = (const int*)d_in[1];
  const int*  batch= (const int*)d_in[2];
  const float* Wq  = (const float*)d_in[3];
  const float* bq  = (const float*)d_in[4];
  const float* Wk  = (const float*)d_in[5];
  const float* bk  = (const float*)d_in[6];
  const float* Wv  = (const float*)d_in[7];
  const float* bv  = (const float*)d_in[8];
  const float* Ws  = (const float*)d_in[9];
  const float* bs  = (const float*)d_in[10];
  float* out = (float*)d_out;

  const int N = in_sizes[0] / D;   // 50000
  const int E = in_sizes[1] / 2;   // 800000
  const int* esrc = ei;
  const int* edst = ei + E;

  float* ws = (float*)d_ws;
  size_t off = 0;
  float* q    = ws + off; off += (size_t)N*D;
  __hip_bfloat16* kb = (__hip_bfloat16*)(ws + off); off += (size_t)N*D/2;
  __hip_bfloat16* vb = (__hip_bfloat16*)(ws + off); off += (size_t)N*D/2;
  float* sp   = ws + off; off += (size_t)N*D;   // s-proj in, relu(out) in-place
  // zero region (cleared by k_wprep): [bcnt | gsum | gcnt]
  int*   bcnt = (int*)(ws + off);  off += (size_t)NB*16;
  float* gsum = ws + off; off += (size_t)NG*D;
  float* gcnt = ws + off; off += NG;
  int*   cnt  = (int*)(ws + off);  off += N;            // fully written by k_bsort
  unsigned* bedge = (unsigned*)(ws + off); off += (size_t)NB*BCAP;
  unsigned short* slots = (unsigned short*)(ws + off); off += (size_t)N*CAP/2;
  short* fragw = (short*)(ws + off); off += 16*256*8/2;  // 64 KB

  const int zn = NB*16 + NG*D + NG;    // ints to zero (bcnt|gsum|gcnt)
  const int nChunk = (E + 255) / 256;  // 3125
  const int nSplit = 256;
  const int nLin   = ((N >> 4) + 1) / 2;   // 1563 (2 strips each)

  k_wprep <<<8, 256, 0, stream>>>(Wq, Wk, Wv, Ws, fragw, bcnt, zn);
  k_fused <<<nSplit + nLin, 256, 0, stream>>>(esrc, edst, bcnt, bedge, E, nChunk,
                                              nSplit, x, fragw, bq, bk, bv, bs,
                                              q, kb, vb, sp, N);
  k_bsort <<<NB, 256, 0, stream>>>(bcnt, bedge, cnt, slots, N);
  k_attend<<<(N+3)/4, 256, 0, stream>>>(q, kb, vb, sp, cnt, slots, N);
  const int rpw = 32;
  int nwaves = (N + rpw - 1) / rpw;
  k_pool <<<(nwaves+3)/4, 256, 0, stream>>>(sp, batch, gsum, gcnt, N, rpw);
  k_final<<<(NG*D+255)/256, 256, 0, stream>>>(gsum, gcnt, out, NG*D);
}